// Round 1
// baseline (161.049 us; speedup 1.0000x reference)
//
#include <hip/hip_runtime.h>
#include <hip/hip_bf16.h>

#define HW 128
#define NPIX 16384          // 128*128
#define CDEP 512
#define NB 8
#define QT 32               // pixels per norm_refs tile

typedef __attribute__((ext_vector_type(8))) short short8;
typedef __attribute__((ext_vector_type(8))) __bf16 bf16x8;
typedef __attribute__((ext_vector_type(4))) float f32x4;

static __device__ inline bf16x8 asbf(short8 v) {
  union { short8 s; bf16x8 b; } u; u.s = v; return u.b;
}

// round-to-nearest-even f32 -> bf16 bits
static __device__ inline unsigned short f2bf(float x) {
  unsigned u = __float_as_uint(x);
  unsigned r = (u + 0x7fffu + ((u >> 16) & 1u)) >> 16;
  return (unsigned short)r;
}

// ---------------- tar normalize: [16384,512] f32 -> bf16 [p,C] ----------------
__global__ __launch_bounds__(256) void k_norm_tar(const float* __restrict__ ft,
                                                  unsigned short* __restrict__ T) {
  int wave = threadIdx.x >> 6, lane = threadIdx.x & 63;
  int p = blockIdx.x * 4 + wave;
  const float* row = ft + (size_t)p * CDEP + lane * 8;
  float4 v0 = *(const float4*)(row);
  float4 v1 = *(const float4*)(row + 4);
  float s = v0.x*v0.x + v0.y*v0.y + v0.z*v0.z + v0.w*v0.w
          + v1.x*v1.x + v1.y*v1.y + v1.z*v1.z + v1.w*v1.w;
  #pragma unroll
  for (int off = 1; off < 64; off <<= 1) s += __shfl_xor(s, off);
  float sc = 1.0f / fmaxf(sqrtf(s), 1e-12f);
  float vv[8] = {v0.x, v0.y, v0.z, v0.w, v1.x, v1.y, v1.z, v1.w};
  short8 pk;
  #pragma unroll
  for (int i = 0; i < 8; ++i) pk[i] = (short)f2bf(vv[i] * sc);
  *(short8*)(T + (size_t)p * CDEP + lane * 8) = pk;
}

// -------- refs normalize + transpose: [b,C,p] f32 -> bf16 [b,p,C] --------
__global__ __launch_bounds__(256) void k_norm_refs(const float* __restrict__ fr,
                                                   unsigned short* __restrict__ R,
                                                   int b_offset) {
  __shared__ float lds[QT][CDEP + 1];   // pad 513: near-conflict-free scalar access
  __shared__ float psum[QT][8];
  __shared__ float inv[QT];
  int b = b_offset + blockIdx.z;
  int q0 = blockIdx.x * QT;
  const float* src = fr + (size_t)b * CDEP * NPIX;
  int t = threadIdx.x;

  // phase A: coalesced float4 loads along q, transpose into LDS [q][c]
  int g = t & 7, cy = t >> 3;           // g: q-group of 4, cy: c row
  #pragma unroll
  for (int it = 0; it < 16; ++it) {
    int c = it * 32 + cy;
    float4 v = *(const float4*)(src + (size_t)c * NPIX + q0 + g * 4);
    lds[g*4 + 0][c] = v.x;
    lds[g*4 + 1][c] = v.y;
    lds[g*4 + 2][c] = v.z;
    lds[g*4 + 3][c] = v.w;
  }
  __syncthreads();

  // phase B: per-pixel sum of squares
  int p = t & 31, part = t >> 5;
  float s = 0.f;
  #pragma unroll
  for (int j = 0; j < 64; ++j) { float v = lds[p][part*64 + j]; s += v * v; }
  psum[p][part] = s;
  __syncthreads();
  if (t < QT) {
    float a = 0.f;
    #pragma unroll
    for (int j = 0; j < 8; ++j) a += psum[t][j];
    inv[t] = 1.0f / fmaxf(sqrtf(a), 1e-12f);
  }
  __syncthreads();

  // phase C: scale, convert, coalesced bf16x2 stores [q][c]
  unsigned short* dst = R + ((size_t)blockIdx.z * NPIX + q0) * CDEP;
  #pragma unroll 4
  for (int j = 0; j < QT; ++j) {
    float sc = inv[j];
    unsigned lo = f2bf(lds[j][2*t]     * sc);
    unsigned hi = f2bf(lds[j][2*t + 1] * sc);
    *(unsigned*)(dst + (size_t)j * CDEP + 2*t) = lo | (hi << 16);
  }
}

// -------- correlation GEMM + softmax --------
// grid (16,16,nb); block 256 = 4 waves; WG: 8x8 pixel block, 16x16 q-window.
__global__ __launch_bounds__(256, 2) void k_corr(const unsigned short* __restrict__ Tb,
                                                 const unsigned short* __restrict__ Rall,
                                                 float* __restrict__ out,
                                                 int b_offset) {
  __shared__ __align__(16) unsigned char ldsb[65536];  // 2 x 32KB B buffers / S scratch
  const int t = threadIdx.x;
  const int lane = t & 63, wave = t >> 6;
  const int wy = wave >> 1, wx = wave & 1;
  const int bx = blockIdx.x, by = blockIdx.y, bz = blockIdx.z;
  const int b = b_offset + bz;
  const short* Rb = (const short*)Rall + (size_t)bz * NPIX * CDEP;
  const short* Tp = (const short*)Tb;

  // ---- A (tar) fragments fully in registers: 16 K-steps ----
  const int mA = lane & 15, kg = lane >> 4;
  const int py = by*8 + wy*4 + (mA >> 2), px = bx*8 + wx*4 + (mA & 3);
  const short* arow = Tp + (size_t)(py * HW + px) * CDEP + kg * 8;
  short8 a[16];
  #pragma unroll
  for (int kk = 0; kk < 16; ++kk) a[kk] = *(const short8*)(arow + kk * 32);

  // ---- staging precompute: thread -> (q, 16B slot) over 8 rounds ----
  const int slot = t & 7, qbase = t >> 3;
  int goff[8]; unsigned gval = 0; int loff[8];
  #pragma unroll
  for (int r = 0; r < 8; ++r) {
    int q = r * 32 + qbase;                 // q in 16x16 window
    int gy = by*8 - 4 + (q >> 4);
    int gx = bx*8 - 4 + (q & 15);
    bool v = ((unsigned)gy < (unsigned)HW) && ((unsigned)gx < (unsigned)HW);
    if (v) gval |= (1u << r);
    goff[r] = v ? ((gy * HW + gx) * CDEP + slot * 8) : 0;
    loff[r] = q * 128 + ((slot * 16) ^ ((q & 7) << 4));   // XOR-swizzled LDS slot
  }

  // ---- B-fragment q indices: wave's 12x12 window as 9 N-tiles ----
  int qn[9];
  #pragma unroll
  for (int tt = 0; tt < 9; ++tt) {
    int idx = tt * 16 + (lane & 15);
    int qly = wy*4 + idx / 12, qlx = wx*4 + idx % 12;
    qn[tt] = qly * 16 + qlx;
  }

  f32x4 acc[9];
  #pragma unroll
  for (int tt = 0; tt < 9; ++tt) acc[tt] = (f32x4){0.f, 0.f, 0.f, 0.f};

  short8 st[8];
  const short8 z8 = {0,0,0,0,0,0,0,0};

  // prologue: stage chunk 0 into buf0
  #pragma unroll
  for (int r = 0; r < 8; ++r)
    st[r] = ((gval >> r) & 1) ? *(const short8*)(Rb + goff[r]) : z8;
  #pragma unroll
  for (int r = 0; r < 8; ++r)
    *(short8*)(ldsb + loff[r]) = st[r];
  __syncthreads();

  #pragma unroll
  for (int ch = 0; ch < 8; ++ch) {
    if (ch < 7) {                          // T14: issue next-chunk loads early
      const short* src = Rb + (ch + 1) * 64;
      #pragma unroll
      for (int r = 0; r < 8; ++r)
        st[r] = ((gval >> r) & 1) ? *(const short8*)(src + goff[r]) : z8;
    }
    const int bufb = (ch & 1) << 15;
    #pragma unroll
    for (int step = 0; step < 2; ++step) {
      short8 af = a[ch * 2 + step];
      #pragma unroll
      for (int tt = 0; tt < 9; ++tt) {
        int q = qn[tt];
        int off = bufb + q * 128 + (((step << 6) | (kg << 4)) ^ ((q & 7) << 4));
        short8 bf = *(const short8*)(ldsb + off);
        acc[tt] = __builtin_amdgcn_mfma_f32_16x16x32_bf16(asbf(af), asbf(bf), acc[tt], 0, 0, 0);
      }
    }
    if (ch < 7) {                          // write next chunk to other buffer
      const int nbuf = ((ch + 1) & 1) << 15;
      #pragma unroll
      for (int r = 0; r < 8; ++r)
        *(short8*)(ldsb + nbuf + loff[r]) = st[r];
      __syncthreads();
    }
  }

  __syncthreads();   // all waves done with B LDS; reuse as S scratch

  // ---- spill S[16 x 144] per wave to LDS (C/D: col=lane&15, row=kg*4+reg) ----
  const int SSTR = 148;
  float* S = (float*)ldsb + wave * 16 * SSTR;
  #pragma unroll
  for (int tt = 0; tt < 9; ++tt) {
    #pragma unroll
    for (int r = 0; r < 4; ++r)
      S[(kg * 4 + r) * SSTR + tt * 16 + (lane & 15)] = acc[tt][r];
  }
  __syncthreads();

  // ---- softmax: 4 lanes per pixel over 81 window values ----
  const int mrow = lane >> 2, s4 = lane & 3;
  const int myy = mrow >> 2, mxx = mrow & 3;
  const float* Srow = S + mrow * SSTR;
  float vals[21];
  float mx = -3.0e38f;
  #pragma unroll
  for (int i = 0; i < 21; ++i) {
    int j = s4 + 4 * i;
    if (j < 81) {
      int dy = j / 9, dx = j % 9;
      float v = Srow[(myy + dy) * 12 + (mxx + dx)];
      vals[i] = v;
      mx = fmaxf(mx, v);
    }
  }
  mx = fmaxf(mx, __shfl_xor(mx, 1));
  mx = fmaxf(mx, __shfl_xor(mx, 2));
  float sum = 0.f;
  #pragma unroll
  for (int i = 0; i < 21; ++i) {
    int j = s4 + 4 * i;
    if (j < 81) { float e = __expf(vals[i] - mx); vals[i] = e; sum += e; }
  }
  sum += __shfl_xor(sum, 1);
  sum += __shfl_xor(sum, 2);
  float rs = 1.0f / sum;
  const int pg = (by*8 + wy*4 + myy) * HW + (bx*8 + wx*4 + mxx);
  float* op = out + ((size_t)b * NPIX + pg) * 81;
  #pragma unroll
  for (int i = 0; i < 21; ++i) {
    int j = s4 + 4 * i;
    if (j < 81) op[j] = vals[i] * rs;
  }
}

extern "C" void kernel_launch(void* const* d_in, const int* in_sizes, int n_in,
                              void* d_out, int out_size, void* d_ws, size_t ws_size,
                              hipStream_t stream) {
  const float* ft = (const float*)d_in[0];
  const float* fr = (const float*)d_in[1];
  float* out = (float*)d_out;
  unsigned short* T = (unsigned short*)d_ws;
  unsigned short* R = T + (size_t)NPIX * CDEP;           // +16MB
  size_t needAll = ((size_t)NPIX * CDEP + (size_t)NB * NPIX * CDEP) * 2;

  k_norm_tar<<<dim3(NPIX / 4), dim3(256), 0, stream>>>(ft, T);
  if (ws_size >= needAll) {
    k_norm_refs<<<dim3(NPIX / QT, 1, NB), dim3(256), 0, stream>>>(fr, R, 0);
    k_corr<<<dim3(16, 16, NB), dim3(256), 0, stream>>>(T, R, out, 0);
  } else {
    for (int bb = 0; bb < NB; ++bb) {
      k_norm_refs<<<dim3(NPIX / QT, 1, 1), dim3(256), 0, stream>>>(fr, R, bb);
      k_corr<<<dim3(16, 16, 1), dim3(256), 0, stream>>>(T, R, out, bb);
    }
  }
}